// Round 1
// baseline (768.359 us; speedup 1.0000x reference)
//
#include <hip/hip_runtime.h>

#define N_NODES 100000
#define N_EDGES 1600000
#define DIM     64
#define HID     256
#define NPB     8
#define BN_EPS  1e-5f

// ws layout (float indices):
//   agg   [0,        6400000)   25.6 MB  (zeroed)
//   deg   [6400000,  6500000)    0.4 MB  (zeroed)
//   stats [6500000,  6500128)   sum[64], sumsq[64] (zeroed)
//   ss    [6500128,  6500256)   scale[64], shift[64]
// zero bytes = 6500128*4 = 26000512

__device__ __forceinline__ float lane_bcast(float v, int k) {
    return __uint_as_float(__builtin_amdgcn_readlane(__float_as_uint(v), (unsigned)k));
}

__global__ __launch_bounds__(256) void k_scatter(const float* __restrict__ h,
                                                 const int* __restrict__ src,
                                                 const int* __restrict__ dst,
                                                 float* __restrict__ agg,
                                                 float* __restrict__ deg) {
    int idx = blockIdx.x * 256 + threadIdx.x;   // (edge, dim) pairs: 102,400,000 < 2^31
    int e = idx >> 6;
    if (e >= N_EDGES) return;
    int d = idx & 63;
    int s = src[e];
    int t = dst[e];
    atomicAdd(&agg[t * 64 + d], h[s * 64 + d]);
    if (d == 0) atomicAdd(&deg[t], 1.0f);
}

__global__ __launch_bounds__(256) void k_mlp(const float* __restrict__ h,
                                             const float* __restrict__ agg,
                                             const float* __restrict__ deg,
                                             const float* __restrict__ W1,
                                             const float* __restrict__ b1,
                                             const float* __restrict__ W2,
                                             const float* __restrict__ b2,
                                             float* __restrict__ y,
                                             float* __restrict__ stats) {
    __shared__ float sW2[HID * DIM];      // 64 KB
    __shared__ float sh_[NPB][HID];       // 8 KB  -> 72 KB total: 2 blocks/CU
    const int t = threadIdx.x;
    const int lane = t & 63;

    // W1 column t in registers (loaded once)
    float w1c[DIM];
#pragma unroll
    for (int k = 0; k < DIM; ++k) w1c[k] = W1[k * HID + t];
    for (int i = t; i < HID * DIM; i += 256) sW2[i] = W2[i];
    const float b1j = b1[t];
    const float b2d = b2[lane];
    __syncthreads();

    float lsum = 0.f, lsq = 0.f;
    const int ngroups = N_NODES / NPB;    // 12500 exactly
    for (int g = blockIdx.x; g < ngroups; g += gridDim.x) {
        const int n0 = g * NPB;
        // x rows into lane registers: xr[n] holds x[n][lane]
        float xr[NPB];
#pragma unroll
        for (int n = 0; n < NPB; ++n) {
            int node = n0 + n;
            float dg = deg[node];
            xr[n] = agg[node * 64 + lane] / fmaxf(dg, 1.0f) + h[node * 64 + lane];
        }
        // L1: thread t computes hidden[n][t] = relu(b1[t] + sum_k x[n][k]*W1[k][t])
        float acc[NPB];
#pragma unroll
        for (int n = 0; n < NPB; ++n) acc[n] = b1j;
#pragma unroll
        for (int k = 0; k < DIM; ++k) {
#pragma unroll
            for (int n = 0; n < NPB; ++n) {
                acc[n] = fmaf(lane_bcast(xr[n], k), w1c[k], acc[n]);
            }
        }
        __syncthreads();   // sh_ no longer read by previous iteration
#pragma unroll
        for (int n = 0; n < NPB; ++n) sh_[n][t] = fmaxf(acc[n], 0.f);
        __syncthreads();
        // L2: thread t -> dim d = lane, nodes nb and nb+4
        const int nb = t >> 6;
        float o0 = b2d, o1 = b2d;
        for (int j4 = 0; j4 < HID; j4 += 4) {
            float wa = sW2[(j4 + 0) * DIM + lane];
            float wb = sW2[(j4 + 1) * DIM + lane];
            float wc = sW2[(j4 + 2) * DIM + lane];
            float wd = sW2[(j4 + 3) * DIM + lane];
            float4 ha = *(const float4*)&sh_[nb][j4];
            float4 hb = *(const float4*)&sh_[nb + 4][j4];
            o0 = fmaf(ha.x, wa, o0); o0 = fmaf(ha.y, wb, o0);
            o0 = fmaf(ha.z, wc, o0); o0 = fmaf(ha.w, wd, o0);
            o1 = fmaf(hb.x, wa, o1); o1 = fmaf(hb.y, wb, o1);
            o1 = fmaf(hb.z, wc, o1); o1 = fmaf(hb.w, wd, o1);
        }
        o0 = fmaxf(o0, 0.f);
        o1 = fmaxf(o1, 0.f);
        y[(n0 + nb) * 64 + lane] = o0;
        y[(n0 + nb + 4) * 64 + lane] = o1;
        lsum += o0 + o1;
        lsq  += o0 * o0 + o1 * o1;
    }
    atomicAdd(&stats[lane], lsum);
    atomicAdd(&stats[64 + lane], lsq);
}

__global__ void k_bnfin(const float* __restrict__ stats,
                        const float* __restrict__ gamma,
                        const float* __restrict__ beta,
                        float* __restrict__ ss) {
    int d = threadIdx.x;
    if (d < 64) {
        const float inv_n = 1.0f / (float)N_NODES;
        float m = stats[d] * inv_n;
        float v = stats[64 + d] * inv_n - m * m;
        float sc = gamma[d] * rsqrtf(v + BN_EPS);
        ss[d] = sc;
        ss[64 + d] = beta[d] - m * sc;
    }
}

__global__ __launch_bounds__(256) void k_apply(const float* __restrict__ ss,
                                               float* __restrict__ out) {
    int i = blockIdx.x * 256 + threadIdx.x;   // float4 index, total N_NODES*16
    if (i >= N_NODES * 16) return;
    float4 v = ((float4*)out)[i];
    int q = i & 15;
    float4 sc = ((const float4*)ss)[q];
    float4 sh = ((const float4*)ss)[16 + q];
    float4 o;
    o.x = fmaf(v.x, sc.x, sh.x);
    o.y = fmaf(v.y, sc.y, sh.y);
    o.z = fmaf(v.z, sc.z, sh.z);
    o.w = fmaf(v.w, sc.w, sh.w);
    ((float4*)out)[i] = o;
}

extern "C" void kernel_launch(void* const* d_in, const int* in_sizes, int n_in,
                              void* d_out, int out_size, void* d_ws, size_t ws_size,
                              hipStream_t stream) {
    const float* h     = (const float*)d_in[0];
    const float* W1    = (const float*)d_in[1];
    const float* b1    = (const float*)d_in[2];
    const float* W2    = (const float*)d_in[3];
    const float* b2    = (const float*)d_in[4];
    const float* gamma = (const float*)d_in[5];
    const float* beta  = (const float*)d_in[6];
    const int*   src   = (const int*)d_in[7];
    const int*   dst   = (const int*)d_in[8];

    float* ws    = (float*)d_ws;
    float* agg   = ws;
    float* deg   = ws + 6400000;
    float* stats = ws + 6500000;
    float* ss    = ws + 6500128;
    float* out   = (float*)d_out;

    hipMemsetAsync(agg, 0, 26000512, stream);

    int scatter_blocks = (N_EDGES * 64) / 256;   // 400000
    k_scatter<<<scatter_blocks, 256, 0, stream>>>(h, src, dst, agg, deg);

    k_mlp<<<512, 256, 0, stream>>>(h, agg, deg, W1, b1, W2, b2, out, stats);

    k_bnfin<<<1, 64, 0, stream>>>(stats, gamma, beta, ss);

    k_apply<<<(N_NODES * 16 + 255) / 256, 256, 0, stream>>>(ss, out);
}

// Round 2
// 736.403 us; speedup vs baseline: 1.0434x; 1.0434x over previous
//
#include <hip/hip_runtime.h>

#define N_NODES 100000
#define N_EDGES 1600000
#define DIM     64
#define HID     256
#define NPB     8
#define BN_EPS  1e-5f
#define NBLK    391   // ceil(100000/256)

// ws layout (4-byte units):
//   deg_i   int[100000]   @ 0
//   stats   float[128]    @ 100000   (sum[64], sumsq[64])
//   ss      float[128]    @ 100128   (scale[64], shift[64])
//   offsets int[100000]   @ 100256
//   cursor  int[100000]   @ 200256
//   bsum    int[512]      @ 300256
//   eidx    int[1600000]  @ 300768
// total 1900768 * 4 = 7.6 MB.  memset covers deg_i+stats = 400512 B.

__device__ __forceinline__ float lane_bcast(float v, int k) {
    return __uint_as_float(__builtin_amdgcn_readlane(__float_as_uint(v), (unsigned)k));
}

__global__ __launch_bounds__(256) void k_deg(const int* __restrict__ dst,
                                             int* __restrict__ deg) {
    int e = blockIdx.x * 256 + threadIdx.x;
    if (e < N_EDGES) atomicAdd(&deg[dst[e]], 1);
}

__global__ __launch_bounds__(256) void k_scan1(const int* __restrict__ deg,
                                               int* __restrict__ offs,
                                               int* __restrict__ bsum) {
    __shared__ int s[256];
    int t = threadIdx.x, b = blockIdx.x;
    int i = b * 256 + t;
    int v = (i < N_NODES) ? deg[i] : 0;
    s[t] = v;
    __syncthreads();
    for (int off = 1; off < 256; off <<= 1) {
        int add = (t >= off) ? s[t - off] : 0;
        __syncthreads();
        s[t] += add;
        __syncthreads();
    }
    if (i < N_NODES) offs[i] = s[t] - v;      // exclusive within block
    if (t == 255) bsum[b] = s[255];
}

__global__ __launch_bounds__(512) void k_scan2(int* __restrict__ bsum) {
    __shared__ int s[512];
    int t = threadIdx.x;
    int v = (t < NBLK) ? bsum[t] : 0;
    s[t] = v;
    __syncthreads();
    for (int off = 1; off < 512; off <<= 1) {
        int add = (t >= off) ? s[t - off] : 0;
        __syncthreads();
        s[t] += add;
        __syncthreads();
    }
    if (t < NBLK) bsum[t] = s[t] - v;         // exclusive block bases
}

__global__ __launch_bounds__(256) void k_scan3(int* __restrict__ offs,
                                               int* __restrict__ cur,
                                               const int* __restrict__ bsum) {
    int i = blockIdx.x * 256 + threadIdx.x;
    if (i < N_NODES) {
        int o = offs[i] + bsum[blockIdx.x];
        offs[i] = o;
        cur[i] = o;
    }
}

__global__ __launch_bounds__(256) void k_fill(const int* __restrict__ src,
                                              const int* __restrict__ dst,
                                              int* __restrict__ cur,
                                              int* __restrict__ eidx) {
    int e = blockIdx.x * 256 + threadIdx.x;
    if (e < N_EDGES) {
        int pos = atomicAdd(&cur[dst[e]], 1);
        eidx[pos] = src[e];
    }
}

__global__ __launch_bounds__(256) void k_mlp(const float* __restrict__ h,
                                             const int* __restrict__ offsets,
                                             const int* __restrict__ deg,
                                             const int* __restrict__ eidx,
                                             const float* __restrict__ W1,
                                             const float* __restrict__ b1,
                                             const float* __restrict__ W2,
                                             const float* __restrict__ b2,
                                             float* __restrict__ y,
                                             float* __restrict__ stats) {
    __shared__ float sW2[HID * DIM];      // 64 KB
    __shared__ float sh_[NPB][HID];       // 8 KB
    __shared__ float sx[NPB][DIM];        // 2 KB  -> 74 KB total: 2 blocks/CU
    const int t = threadIdx.x;
    const int lane = t & 63;
    const int w = t >> 6;                 // wave id 0..3

    float w1c[DIM];
#pragma unroll
    for (int k = 0; k < DIM; ++k) w1c[k] = W1[k * HID + t];
    for (int i = t; i < HID * DIM; i += 256) sW2[i] = W2[i];
    const float b1j = b1[t];
    const float b2d = b2[lane];
    __syncthreads();

    float lsum = 0.f, lsq = 0.f;
    const int ngroups = N_NODES / NPB;    // 12500
    for (int g = blockIdx.x; g < ngroups; g += gridDim.x) {
        const int n0 = g * NPB;
        // gather: wave w produces x rows for nodes n0+2w, n0+2w+1
#pragma unroll
        for (int r = 0; r < 2; ++r) {
            int node = n0 + 2 * w + r;
            int off = offsets[node];
            int dg = deg[node];
            float s0 = 0.f, s1 = 0.f;
            int j = 0;
            for (; j + 1 < dg; j += 2) {
                int a = eidx[off + j];
                int b = eidx[off + j + 1];
                s0 += h[a * 64 + lane];
                s1 += h[b * 64 + lane];
            }
            if (j < dg) s0 += h[eidx[off + j] * 64 + lane];
            s0 += s1;
            sx[2 * w + r][lane] =
                s0 / (float)max(dg, 1) + h[node * 64 + lane];
        }
        __syncthreads();                  // sx visible; also fences prev sh_ reads
        float xr[NPB];
#pragma unroll
        for (int n = 0; n < NPB; ++n) xr[n] = sx[n][lane];
        // L1: thread t computes hidden[n][t]
        float acc[NPB];
#pragma unroll
        for (int n = 0; n < NPB; ++n) acc[n] = b1j;
#pragma unroll
        for (int k = 0; k < DIM; ++k) {
#pragma unroll
            for (int n = 0; n < NPB; ++n)
                acc[n] = fmaf(lane_bcast(xr[n], k), w1c[k], acc[n]);
        }
        __syncthreads();                  // all xr/sx reads done before sh_ write
#pragma unroll
        for (int n = 0; n < NPB; ++n) sh_[n][t] = fmaxf(acc[n], 0.f);
        __syncthreads();
        // L2: thread t -> dim = lane, nodes nb and nb+4
        const int nb = w;
        float o0 = b2d, o1 = b2d;
        for (int j4 = 0; j4 < HID; j4 += 4) {
            float wa = sW2[(j4 + 0) * DIM + lane];
            float wb = sW2[(j4 + 1) * DIM + lane];
            float wc = sW2[(j4 + 2) * DIM + lane];
            float wd = sW2[(j4 + 3) * DIM + lane];
            float4 ha = *(const float4*)&sh_[nb][j4];
            float4 hb = *(const float4*)&sh_[nb + 4][j4];
            o0 = fmaf(ha.x, wa, o0); o0 = fmaf(ha.y, wb, o0);
            o0 = fmaf(ha.z, wc, o0); o0 = fmaf(ha.w, wd, o0);
            o1 = fmaf(hb.x, wa, o1); o1 = fmaf(hb.y, wb, o1);
            o1 = fmaf(hb.z, wc, o1); o1 = fmaf(hb.w, wd, o1);
        }
        o0 = fmaxf(o0, 0.f);
        o1 = fmaxf(o1, 0.f);
        y[(n0 + nb) * 64 + lane] = o0;
        y[(n0 + nb + 4) * 64 + lane] = o1;
        lsum += o0 + o1;
        lsq  += o0 * o0 + o1 * o1;
    }
    atomicAdd(&stats[lane], lsum);
    atomicAdd(&stats[64 + lane], lsq);
}

__global__ void k_bnfin(const float* __restrict__ stats,
                        const float* __restrict__ gamma,
                        const float* __restrict__ beta,
                        float* __restrict__ ss) {
    int d = threadIdx.x;
    if (d < 64) {
        const float inv_n = 1.0f / (float)N_NODES;
        float m = stats[d] * inv_n;
        float v = stats[64 + d] * inv_n - m * m;
        float sc = gamma[d] * rsqrtf(v + BN_EPS);
        ss[d] = sc;
        ss[64 + d] = beta[d] - m * sc;
    }
}

__global__ __launch_bounds__(256) void k_apply(const float* __restrict__ ss,
                                               float* __restrict__ out) {
    int i = blockIdx.x * 256 + threadIdx.x;   // float4 index, N_NODES*16 total
    if (i >= N_NODES * 16) return;
    float4 v = ((float4*)out)[i];
    int q = i & 15;
    float4 sc = ((const float4*)ss)[q];
    float4 sh = ((const float4*)ss)[16 + q];
    float4 o;
    o.x = fmaf(v.x, sc.x, sh.x);
    o.y = fmaf(v.y, sc.y, sh.y);
    o.z = fmaf(v.z, sc.z, sh.z);
    o.w = fmaf(v.w, sc.w, sh.w);
    ((float4*)out)[i] = o;
}

extern "C" void kernel_launch(void* const* d_in, const int* in_sizes, int n_in,
                              void* d_out, int out_size, void* d_ws, size_t ws_size,
                              hipStream_t stream) {
    const float* h     = (const float*)d_in[0];
    const float* W1    = (const float*)d_in[1];
    const float* b1    = (const float*)d_in[2];
    const float* W2    = (const float*)d_in[3];
    const float* b2    = (const float*)d_in[4];
    const float* gamma = (const float*)d_in[5];
    const float* beta  = (const float*)d_in[6];
    const int*   src   = (const int*)d_in[7];
    const int*   dst   = (const int*)d_in[8];

    int*   wsi     = (int*)d_ws;
    int*   deg     = wsi;
    float* stats   = (float*)(wsi + 100000);
    float* ss      = (float*)(wsi + 100128);
    int*   offsets = wsi + 100256;
    int*   cursor  = wsi + 200256;
    int*   bsum    = wsi + 300256;
    int*   eidx    = wsi + 300768;
    float* out     = (float*)d_out;

    hipMemsetAsync(deg, 0, 400512, stream);   // deg_i + stats

    const int EB = (N_EDGES + 255) / 256;     // 6250
    k_deg<<<EB, 256, 0, stream>>>(dst, deg);
    k_scan1<<<NBLK, 256, 0, stream>>>(deg, offsets, bsum);
    k_scan2<<<1, 512, 0, stream>>>(bsum);
    k_scan3<<<NBLK, 256, 0, stream>>>(offsets, cursor, bsum);
    k_fill<<<EB, 256, 0, stream>>>(src, dst, cursor, eidx);

    k_mlp<<<512, 256, 0, stream>>>(h, offsets, deg, eidx, W1, b1, W2, b2, out, stats);

    k_bnfin<<<1, 64, 0, stream>>>(stats, gamma, beta, ss);
    k_apply<<<(N_NODES * 16 + 255) / 256, 256, 0, stream>>>(ss, out);
}

// Round 3
// 414.025 us; speedup vs baseline: 1.8558x; 1.7786x over previous
//
#include <hip/hip_runtime.h>

#define N_NODES 100000
#define N_EDGES 1600000
#define DIM     64
#define HID     256
#define BN_EPS  1e-5f
#define NBLK    391            // ceil(100000/256)
#define NGROUPS 1563           // ceil(100000/64) groups of 64 rows
#define MLP_BLOCKS 512

typedef short bf16x8 __attribute__((ext_vector_type(8)));
typedef float f32x4  __attribute__((ext_vector_type(4)));

// ws layout (4-byte units):
//   deg     int[100000]        @ 0
//   stats   float[128]         @ 100000   (sum[64], sumsq[64])
//   ss      float[128]         @ 100128   (scale[64], shift[64])
//   offsets int[100000]        @ 100256
//   cursor  int[100000]        @ 200256
//   bsum    int[512]           @ 300256
//   w1t_g   bf16[256*64]       @ 300768   (8192 ints)  [n][k]
//   w2t_g   bf16[64*256]       @ 308960   (8192 ints)  [d][k2]
//   eidx    int[1600000]       @ 317152
//   xb      bf16[100032*64]    @ 1917152  (3201024 ints, 16B aligned)
// memset covers deg+stats = 400512 B

__device__ __forceinline__ unsigned short f2bf(float x) {
    unsigned int u = __float_as_uint(x);
    unsigned int r = (u + 0x7FFFu + ((u >> 16) & 1u)) >> 16;
    return (unsigned short)r;
}

__global__ __launch_bounds__(256) void k_deg(const int* __restrict__ dst,
                                             int* __restrict__ deg) {
    int e = blockIdx.x * 256 + threadIdx.x;
    if (e < N_EDGES) atomicAdd(&deg[dst[e]], 1);
}

__global__ __launch_bounds__(256) void k_scan1(const int* __restrict__ deg,
                                               int* __restrict__ offs,
                                               int* __restrict__ bsum) {
    __shared__ int s[256];
    int t = threadIdx.x, b = blockIdx.x;
    int i = b * 256 + t;
    int v = (i < N_NODES) ? deg[i] : 0;
    s[t] = v;
    __syncthreads();
    for (int off = 1; off < 256; off <<= 1) {
        int add = (t >= off) ? s[t - off] : 0;
        __syncthreads();
        s[t] += add;
        __syncthreads();
    }
    if (i < N_NODES) offs[i] = s[t] - v;
    if (t == 255) bsum[b] = s[255];
}

__global__ __launch_bounds__(512) void k_scan2(int* __restrict__ bsum) {
    __shared__ int s[512];
    int t = threadIdx.x;
    int v = (t < NBLK) ? bsum[t] : 0;
    s[t] = v;
    __syncthreads();
    for (int off = 1; off < 512; off <<= 1) {
        int add = (t >= off) ? s[t - off] : 0;
        __syncthreads();
        s[t] += add;
        __syncthreads();
    }
    if (t < NBLK) bsum[t] = s[t] - v;
}

__global__ __launch_bounds__(256) void k_scan3(int* __restrict__ offs,
                                               int* __restrict__ cur,
                                               const int* __restrict__ bsum) {
    int i = blockIdx.x * 256 + threadIdx.x;
    if (i < N_NODES) {
        int o = offs[i] + bsum[blockIdx.x];
        offs[i] = o;
        cur[i] = o;
    }
}

__global__ __launch_bounds__(256) void k_fill(const int* __restrict__ src,
                                              const int* __restrict__ dst,
                                              int* __restrict__ cur,
                                              int* __restrict__ eidx) {
    int e = blockIdx.x * 256 + threadIdx.x;
    if (e < N_EDGES) {
        int pos = atomicAdd(&cur[dst[e]], 1);
        eidx[pos] = src[e];
    }
}

// weight prep: w1t_g[n][k]=bf16(W1[k][n]); w2t_g[d][k2]=bf16(W2[k2][d]); zero x pad
__global__ __launch_bounds__(256) void k_wprep(const float* __restrict__ W1,
                                               const float* __restrict__ W2,
                                               unsigned short* __restrict__ w1t,
                                               unsigned short* __restrict__ w2t,
                                               unsigned short* __restrict__ xb) {
    int id = blockIdx.x * 256 + threadIdx.x;     // 136*256 = 34816
    if (id < 16384) {                            // n*64+k
        int n = id >> 6, k = id & 63;
        w1t[id] = f2bf(W1[k * 256 + n]);
    } else if (id < 32768) {
        int i2 = id - 16384;                     // d*256+k2
        int d = i2 >> 8, k2 = i2 & 255;
        w2t[i2] = f2bf(W2[k2 * 64 + d]);
    } else {                                     // zero 32 pad rows of xb
        xb[100000 * 64 + (id - 32768)] = 0;
    }
}

// one wave per node: mean-gather + self, write bf16 x
__global__ __launch_bounds__(256) void k_gather(const float* __restrict__ h,
                                                const int* __restrict__ offsets,
                                                const int* __restrict__ deg,
                                                const int* __restrict__ eidx,
                                                unsigned short* __restrict__ xb) {
    const int lane = threadIdx.x & 63;
    const int node = blockIdx.x * 4 + (threadIdx.x >> 6);   // 25000*4 = 100000
    const int off = __builtin_amdgcn_readfirstlane(offsets[node]);
    const int dg  = __builtin_amdgcn_readfirstlane(deg[node]);
    const float* hl = h + lane;
    float own = hl[(size_t)node * 64];
    float s0 = 0.f, s1 = 0.f, s2 = 0.f, s3 = 0.f;
    int j = off, end = off + dg;
    for (; j + 3 < end; j += 4) {
        int a = eidx[j], b = eidx[j + 1], c = eidx[j + 2], d = eidx[j + 3];
        s0 += hl[(size_t)a * 64];
        s1 += hl[(size_t)b * 64];
        s2 += hl[(size_t)c * 64];
        s3 += hl[(size_t)d * 64];
    }
    for (; j < end; ++j) s0 += hl[(size_t)eidx[j] * 64];
    float x = (s0 + s1) + (s2 + s3);
    x = x / (float)max(dg, 1) + own;
    xb[(size_t)node * 64 + lane] = f2bf(x);
}

// fused 2-layer MFMA MLP + stats accumulation
__global__ __launch_bounds__(256, 2) void k_mlp(const unsigned short* __restrict__ xb,
                                                const unsigned short* __restrict__ w1t,
                                                const unsigned short* __restrict__ w2t,
                                                const float* __restrict__ b1,
                                                const float* __restrict__ b2,
                                                float* __restrict__ y,
                                                float* __restrict__ stats) {
    __shared__ unsigned short sW1[256][72];   // [n][k]  36864 B (2-way banks: free)
    __shared__ unsigned short sW2[64][264];   // [d][k2] 33792 B
    __shared__ unsigned short sH[4][16][72];  // per-wave hidden chunk [m][k2l] 9216 B
    __shared__ float sB1[256];
    __shared__ float sB2[64];
    const int t = threadIdx.x;
    const int lane = t & 63;
    const int w = t >> 6;
    const int l15 = lane & 15;
    const int g4 = lane >> 4;       // 0..3

    // stage weights (bf16, pre-transposed) into LDS, 16B chunks
    for (int i = t; i < 2048; i += 256) {          // W1t: 256 rows x 8 chunks
        int row = i >> 3, c = i & 7;
        *(uint4*)&sW1[row][c * 8] = *(const uint4*)(w1t + row * 64 + c * 8);
    }
    for (int i = t; i < 2048; i += 256) {          // W2t: 64 rows x 32 chunks
        int row = i >> 5, c = i & 31;
        *(uint4*)&sW2[row][c * 8] = *(const uint4*)(w2t + row * 256 + c * 8);
    }
    sB1[t] = b1[t];
    if (t < 64) sB2[t] = b2[t];
    __syncthreads();

    float lsum[4] = {0.f, 0.f, 0.f, 0.f};
    float lsq[4]  = {0.f, 0.f, 0.f, 0.f};

    for (int g = blockIdx.x; g < NGROUPS; g += MLP_BLOCKS) {
        const int m0 = g * 64 + w * 16;
        // x B-fragments (x^T as B operand): lane holds x[m0+l15][s*32+g4*8 .. +7]
        const unsigned short* xrow = xb + (size_t)(m0 + l15) * 64 + g4 * 8;
        bf16x8 xf0 = *(const bf16x8*)(xrow);
        bf16x8 xf1 = *(const bf16x8*)(xrow + 32);

        f32x4 oacc[4];
#pragma unroll
        for (int dt = 0; dt < 4; ++dt) oacc[dt] = (f32x4){0.f, 0.f, 0.f, 0.f};

#pragma unroll
        for (int p = 0; p < 4; ++p) {             // k2 chunks of 64
#pragma unroll
            for (int nt2 = 0; nt2 < 4; ++nt2) {   // L1: hidden^T tiles
                const int n0 = p * 64 + nt2 * 16;
                f32x4 hacc = (f32x4){0.f, 0.f, 0.f, 0.f};
                bf16x8 wf0 = *(const bf16x8*)&sW1[n0 + l15][g4 * 8];
                bf16x8 wf1 = *(const bf16x8*)&sW1[n0 + l15][32 + g4 * 8];
                hacc = __builtin_amdgcn_mfma_f32_16x16x32_bf16(wf0, xf0, hacc, 0, 0, 0);
                hacc = __builtin_amdgcn_mfma_f32_16x16x32_bf16(wf1, xf1, hacc, 0, 0, 0);
                // lane holds hidden[m=l15][n = n0 + g4*4 + r]
                float4 bq = *(const float4*)&sB1[n0 + g4 * 4];
                ushort4 pk;
                pk.x = f2bf(fmaxf(hacc[0] + bq.x, 0.f));
                pk.y = f2bf(fmaxf(hacc[1] + bq.y, 0.f));
                pk.z = f2bf(fmaxf(hacc[2] + bq.z, 0.f));
                pk.w = f2bf(fmaxf(hacc[3] + bq.w, 0.f));
                *(ushort4*)&sH[w][l15][nt2 * 16 + g4 * 4] = pk;
            }
#pragma unroll
            for (int s2 = 0; s2 < 2; ++s2) {      // L2 partial over this chunk
                bf16x8 a2 = *(const bf16x8*)&sH[w][l15][s2 * 32 + g4 * 8];
#pragma unroll
                for (int dt = 0; dt < 4; ++dt) {
                    bf16x8 w2f = *(const bf16x8*)&sW2[dt * 16 + l15]
                                                    [p * 64 + s2 * 32 + g4 * 8];
                    oacc[dt] = __builtin_amdgcn_mfma_f32_16x16x32_bf16(
                        a2, w2f, oacc[dt], 0, 0, 0);
                }
            }
        }
        // epilogue: bias + relu, store y, accumulate stats
#pragma unroll
        for (int dt = 0; dt < 4; ++dt) {
            float bv = sB2[dt * 16 + l15];
#pragma unroll
            for (int r = 0; r < 4; ++r) {
                int mabs = m0 + g4 * 4 + r;
                float val = fmaxf(oacc[dt][r] + bv, 0.f);
                if (mabs < N_NODES) {
                    y[(size_t)mabs * 64 + dt * 16 + l15] = val;
                    lsum[dt] += val;
                    lsq[dt] += val * val;
                }
            }
        }
    }

    // block-level stats reduction (reuse sW1 memory)
    __syncthreads();
    float* sred = (float*)&sW1[0][0];             // [256][8]
#pragma unroll
    for (int dt = 0; dt < 4; ++dt) {
        sred[t * 8 + dt] = lsum[dt];
        sred[t * 8 + 4 + dt] = lsq[dt];
    }
    __syncthreads();
    if (t < 128) {
        int issq = (t >= 64) ? 4 : 0;
        int d = t & 63;
        int dt = d >> 4, dl = d & 15;
        float acc = 0.f;
        for (int i = 0; i < 16; ++i) acc += sred[(dl + 16 * i) * 8 + issq + dt];
        atomicAdd(&stats[(issq ? 64 : 0) + d], acc);
    }
}

__global__ void k_bnfin(const float* __restrict__ stats,
                        const float* __restrict__ gamma,
                        const float* __restrict__ beta,
                        float* __restrict__ ss) {
    int d = threadIdx.x;
    if (d < 64) {
        const float inv_n = 1.0f / (float)N_NODES;
        float m = stats[d] * inv_n;
        float v = stats[64 + d] * inv_n - m * m;
        float sc = gamma[d] * rsqrtf(v + BN_EPS);
        ss[d] = sc;
        ss[64 + d] = beta[d] - m * sc;
    }
}

__global__ __launch_bounds__(256) void k_apply(const float* __restrict__ ss,
                                               float* __restrict__ out) {
    int i = blockIdx.x * 256 + threadIdx.x;
    if (i >= N_NODES * 16) return;
    float4 v = ((float4*)out)[i];
    int q = i & 15;
    float4 sc = ((const float4*)ss)[q];
    float4 sh = ((const float4*)ss)[16 + q];
    float4 o;
    o.x = fmaf(v.x, sc.x, sh.x);
    o.y = fmaf(v.y, sc.y, sh.y);
    o.z = fmaf(v.z, sc.z, sh.z);
    o.w = fmaf(v.w, sc.w, sh.w);
    ((float4*)out)[i] = o;
}

extern "C" void kernel_launch(void* const* d_in, const int* in_sizes, int n_in,
                              void* d_out, int out_size, void* d_ws, size_t ws_size,
                              hipStream_t stream) {
    const float* h     = (const float*)d_in[0];
    const float* W1    = (const float*)d_in[1];
    const float* b1    = (const float*)d_in[2];
    const float* W2    = (const float*)d_in[3];
    const float* b2    = (const float*)d_in[4];
    const float* gamma = (const float*)d_in[5];
    const float* beta  = (const float*)d_in[6];
    const int*   src   = (const int*)d_in[7];
    const int*   dst   = (const int*)d_in[8];

    int* wsi = (int*)d_ws;
    int*            deg     = wsi;
    float*          stats   = (float*)(wsi + 100000);
    float*          ss      = (float*)(wsi + 100128);
    int*            offsets = wsi + 100256;
    int*            cursor  = wsi + 200256;
    int*            bsum    = wsi + 300256;
    unsigned short* w1t     = (unsigned short*)(wsi + 300768);
    unsigned short* w2t     = (unsigned short*)(wsi + 308960);
    int*            eidx    = wsi + 317152;
    unsigned short* xb      = (unsigned short*)(wsi + 1917152);
    float*          out     = (float*)d_out;

    hipMemsetAsync(deg, 0, 400512, stream);       // deg + stats

    const int EB = (N_EDGES + 255) / 256;         // 6250
    k_deg<<<EB, 256, 0, stream>>>(dst, deg);
    k_scan1<<<NBLK, 256, 0, stream>>>(deg, offsets, bsum);
    k_scan2<<<1, 512, 0, stream>>>(bsum);
    k_scan3<<<NBLK, 256, 0, stream>>>(offsets, cursor, bsum);
    k_fill<<<EB, 256, 0, stream>>>(src, dst, cursor, eidx);
    k_wprep<<<136, 256, 0, stream>>>(W1, W2, w1t, w2t, xb);
    k_gather<<<25000, 256, 0, stream>>>(h, offsets, deg, eidx, xb);
    k_mlp<<<MLP_BLOCKS, 256, 0, stream>>>(xb, w1t, w2t, b1, b2, out, stats);
    k_bnfin<<<1, 64, 0, stream>>>(stats, gamma, beta, ss);
    k_apply<<<(N_NODES * 16 + 255) / 256, 256, 0, stream>>>(ss, out);
}